// Round 13
// baseline (110.654 us; speedup 1.0000x reference)
//
#include <hip/hip_runtime.h>
#include <math.h>

#define CLAMPV 1000000.0f
#define PI_F     3.14159274f
#define HALFPI_F 1.57079633f
#define LN2_F    0.69314718f      // ln2
#define L2E_F    1.44269504f      // 1/ln2
#define C1_F     0.17328680f      // ln2/4      : exp2-arg coeff, complex nodes (log2 of |.|^2)
#define C2_F     0.05515890f      // ln2/(4*pi) : rev-arg coeff, complex nodes
#define C2R_F    0.11031780f      // ln2/(2*pi) : rev-arg coeff, real-child nodes
#define BIGM_F   3.0e38f          // taint-fold multiplier: any nonzero |imag| -> -inf side

typedef float v2f __attribute__((ext_vector_type(2)));

__device__ __forceinline__ v2f vb(float s) { return (v2f){s, s}; }
__device__ __forceinline__ v2f vfma(v2f a, v2f b, v2f c) { return __builtin_elementwise_fma(a, b, c); }

// Wave-uniform gate pointer -> s_load on the scalar pipe.
__device__ __forceinline__ const float* gptr(const float* __restrict__ g, int node) {
    return g + 6 * __builtin_amdgcn_readfirstlane(node);
}

// sanitize: nan -> 0, clamp to [-1e6,1e6] (med3 absorbs +-inf)
__device__ __forceinline__ v2f sanitv(v2f v) {
    v2f c;
    c.x = __builtin_amdgcn_fmed3f(v.x, -CLAMPV, CLAMPV);
    c.y = __builtin_amdgcn_fmed3f(v.y, -CLAMPV, CLAMPV);
    c.x = (v.x != v.x) ? 0.0f : c.x;
    c.y = (v.y != v.y) ? 0.0f : c.y;
    return c;
}

// packed fast atan2, deg-9 minimax; (+0, x<0) -> +pi matches numpy for the
// exact-zero-imag chains (imag forced to +0 upstream).
__device__ __forceinline__ v2f fatan2v(v2f y, v2f x) {
    v2f ax = __builtin_elementwise_abs(x);
    v2f ay = __builtin_elementwise_abs(y);
    v2f mx = __builtin_elementwise_max(ax, ay);
    v2f mn = __builtin_elementwise_min(ax, ay);
    v2f r  = (v2f){__builtin_amdgcn_rcpf(mx.x), __builtin_amdgcn_rcpf(mx.y)};
    v2f t  = mn * r;
    v2f z  = t * t;
    v2f p  = vfma(z, vfma(z, vfma(z, vfma(z,
             vb(0.02083510f), vb(-0.08513300f)), vb(0.18014100f)), vb(-0.33029950f)),
             vb(0.99986600f));
    p = p * t;
    p.x = (ay.x > ax.x) ? (HALFPI_F - p.x) : p.x;
    p.y = (ay.y > ax.y) ? (HALFPI_F - p.y) : p.y;
    p.x = (x.x < 0.0f) ? (PI_F - p.x) : p.x;
    p.y = (x.y < 0.0f) ? (PI_F - p.y) : p.y;
    p.x = copysignf(p.x, y.x);
    p.y = copysignf(p.y, y.y);
    return p;
}

// exp2/sin/cos tail from pre-folded args: r = 2^e ; angle = f0 revolutions.
__device__ __forceinline__ void exp_tailv(v2f e, v2f f0, v2f& ore, v2f& oim) {
    v2f r = (v2f){__builtin_amdgcn_exp2f(e.x), __builtin_amdgcn_exp2f(e.y)};
    v2f f = (v2f){__builtin_amdgcn_fractf(f0.x), __builtin_amdgcn_fractf(f0.y)};
    v2f sn = (v2f){__builtin_amdgcn_sinf(f.x), __builtin_amdgcn_sinf(f.y)};
    v2f cs = (v2f){__builtin_amdgcn_cosf(f.x), __builtin_amdgcn_cosf(f.y)};
    ore = sanitv(r * cs);
    oim = sanitv(r * sn);
}

// Real-positive fast path body: children real, u > 0, v > 0 across the wave.
//   out = ( min(2^(ln2*log2(u)*log2(v)), 1e6), +0 )
__device__ __forceinline__ void fast_rp(v2f ure, v2f vre, v2f& ore, v2f& oim) {
    v2f L2u = (v2f){__builtin_amdgcn_logf(ure.x), __builtin_amdgcn_logf(ure.y)};
    v2f L2v = (v2f){__builtin_amdgcn_logf(vre.x), __builtin_amdgcn_logf(vre.y)};
    v2f e = (vb(LN2_F) * L2u) * L2v;
    v2f r = (v2f){__builtin_amdgcn_exp2f(e.x), __builtin_amdgcn_exp2f(e.y)};
    v2f c = __builtin_elementwise_min(r, vb(CLAMPV));
    c.x = (r.x != r.x) ? 0.0f : c.x;
    c.y = (r.y != r.y) ? 0.0f : c.y;
    ore = c;
    oim = vb(0.0f);
}

// General node (children may be complex). Folded taint test:
//   bad  <=>  min(u,v) <= 0  OR  |lim|+|rim| > 0  OR NaN
//        <=>  !( min(u,v) - (|lim|+|rim|)*3e38  >  0 )      (ngt is NaN-true)
// 2 pk-ops + 2 v_cmp + 1 s_or, replacing the previous 6-ballot chain.
// (Denormal imag parts fold to zero — phase error ~1e-38, far below tolerance.)
__device__ __forceinline__ void node_any(
    v2f lre, v2f lim, v2f rre, v2f rim,
    v2f x, const float* __restrict__ g,
    v2f& ore, v2f& oim)
{
    float g0 = g[0], g1 = g[1], g2 = g[2], g3 = g[3], g4 = g[4], g5 = g[5];
    v2f ure = vfma(vb(g2), lre, vfma(vb(g1), x, vb(g0)));
    v2f vre = vfma(vb(g5), rre, vfma(vb(g4), x, vb(g3)));
    v2f mn = __builtin_elementwise_min(ure, vre);

    v2f simag = __builtin_elementwise_abs(lim) + __builtin_elementwise_abs(rim);
    v2f w = vfma(simag, vb(-BIGM_F), mn);
    unsigned long long bad = __ballot(!(w.x > 0.0f)) | __ballot(!(w.y > 0.0f));

    if (bad == 0ULL) {
        fast_rp(ure, vre, ore, oim);
    } else {
        // exact complex path; fma(g2, lim, +0) forces -0 -> +0 (load-bearing
        // for the atan2 branch choice when a child's imag is exactly zero)
        v2f uim = vfma(vb(g2), lim, vb(0.0f));
        v2f vim = vfma(vb(g5), rim, vb(0.0f));

        v2f nu = vfma(ure, ure, uim * uim);
        v2f nv = vfma(vre, vre, vim * vim);
        v2f L2u = (v2f){__builtin_amdgcn_logf(nu.x), __builtin_amdgcn_logf(nu.y)};
        v2f L2v = (v2f){__builtin_amdgcn_logf(nv.x), __builtin_amdgcn_logf(nv.y)};
        v2f Au = fatan2v(uim, ure);
        v2f Av = fatan2v(vim, vre);

        v2f t2 = vb(L2E_F) * (Au * Av);
        v2f e  = vfma(vb(C1_F) * L2u, L2v, -t2);
        v2f s2 = vfma(L2u, Av, Au * L2v);
        v2f f0 = vb(C2_F) * s2;
        exp_tailv(e, f0, ore, oim);
    }
}

// Round-0 node: children are real leaf values. ngt form is NaN-safe.
__device__ __forceinline__ void node_r0(
    v2f l, v2f r, v2f x, const float* __restrict__ g,
    v2f& ore, v2f& oim)
{
    float g0 = g[0], g1 = g[1], g2 = g[2], g3 = g[3], g4 = g[4], g5 = g[5];
    v2f u = vfma(vb(g2), l, vfma(vb(g1), x, vb(g0)));
    v2f v = vfma(vb(g5), r, vfma(vb(g4), x, vb(g3)));
    v2f mn = __builtin_elementwise_min(u, v);

    unsigned long long bad = __ballot(!(mn.x > 0.0f)) | __ballot(!(mn.y > 0.0f));

    if (bad == 0ULL) {
        fast_rp(u, v, ore, oim);
    } else {
        v2f au = __builtin_elementwise_abs(u);
        v2f av = __builtin_elementwise_abs(v);
        v2f L2u = (v2f){__builtin_amdgcn_logf(au.x), __builtin_amdgcn_logf(au.y)};
        v2f L2v = (v2f){__builtin_amdgcn_logf(av.x), __builtin_amdgcn_logf(av.y)};
        v2f Au, Av;
        Au.x = (u.x < 0.0f) ? PI_F : 0.0f;
        Au.y = (u.y < 0.0f) ? PI_F : 0.0f;
        Av.x = (v.x < 0.0f) ? PI_F : 0.0f;
        Av.y = (v.y < 0.0f) ? PI_F : 0.0f;

        v2f t2 = vb(L2E_F) * (Au * Av);
        v2f e  = vfma(vb(LN2_F) * L2u, L2v, -t2);
        v2f s2 = vfma(L2u, Av, Au * L2v);
        v2f f0 = vb(C2R_F) * s2;
        exp_tailv(e, f0, ore, oim);
    }
}

// Block: 64 lanes x 16 subtrees (1024 threads = 16 waves). Each lane owns 2
// batch elements (e0 = blk*128 + lane, e1 = e0 + 64), math 2-wide packed.
// Per thread: 64-leaf subtree, rounds 0-5 in registers (static merge).
// Tail rounds 6-9 parallelized across waves (8/4/2/1) with barriers.
__global__ __launch_bounds__(1024, 8) void EMLTree1DLinear_kernel(
    const float* __restrict__ x_g,      // [batch]
    const float* __restrict__ leaf_g,   // [1024][2]
    const float* __restrict__ gate_g,   // [1023][2][3] flat
    float* __restrict__ out,            // [batch][2] interleaved complex (or [batch] real)
    int batch, int out_real_only)
{
    __shared__ float4 s_t[30][64];        // 30720 B: rows 0..15 round-5 roots,
                                          // 16..23 r6, 24..27 r7, 28..29 r8
    const int lane = threadIdx.x;         // 0..63
    const int s    = threadIdx.y;         // subtree, 0..15

    const int e0 = blockIdx.x * 128 + lane;
    const v2f x2 = (v2f){x_g[e0], x_g[e0 + 64]};

    v2f cAre, cAim, cBre, cBim, rootre, rootim;

    // 4 groups of 16 leaves; rolled to keep the dual-path body I$-resident.
#pragma clang loop unroll(disable)
    for (int q = 0; q < 4; ++q) {
        const int jq = 64 * s + 16 * q;    // leftmost leaf of this group
        v2f r2re[2], r2im[2];
        v2f h1re = vb(0.0f), h1im = vb(0.0f);
        v2f cre, cim;

#pragma unroll
        for (int p = 0; p < 4; ++p) {
            const int j = jq + 4 * p;
            // 4 leaves via scalar loads (wave-uniform address)
            const float* L = leaf_g + 2 * __builtin_amdgcn_readfirstlane(j);
            v2f l0 = vfma(vb(L[1]), x2, vb(L[0]));
            v2f l1 = vfma(vb(L[3]), x2, vb(L[2]));
            v2f l2 = vfma(vb(L[5]), x2, vb(L[4]));
            v2f l3 = vfma(vb(L[7]), x2, vb(L[6]));

            // round 0: nodes (j>>1), (j>>1)+1
            v2f Are, Aim, Bre, Bim;
            node_r0(l0, l1, x2, gptr(gate_g, j >> 1), Are, Aim);
            node_r0(l2, l3, x2, gptr(gate_g, (j >> 1) + 1), Bre, Bim);

            // round 1: node 512 + (j>>2)
            v2f r1re, r1im;
            node_any(Are, Aim, Bre, Bim, x2, gptr(gate_g, 512 + (j >> 2)), r1re, r1im);

            if (p & 1) {
                // round 2: node 768 + (j>>3)
                node_any(h1re, h1im, r1re, r1im, x2,
                         gptr(gate_g, 768 + (j >> 3)), r2re[p >> 1], r2im[p >> 1]);
            } else {
                h1re = r1re; h1im = r1im;
            }
        }
        // round 3: node 896 + (jq>>4)
        node_any(r2re[0], r2im[0], r2re[1], r2im[1], x2,
                 gptr(gate_g, 896 + (jq >> 4)), cre, cim);

        // rounds 4-5: static register merge (positions 4s+q at round 3)
        if (q == 0) {
            cAre = cre; cAim = cim;
        } else if (q == 1) {
            node_any(cAre, cAim, cre, cim, x2, gptr(gate_g, 960 + 2 * s), cBre, cBim);
        } else if (q == 2) {
            cAre = cre; cAim = cim;
        } else {
            v2f tre, tim;
            node_any(cAre, cAim, cre, cim, x2, gptr(gate_g, 961 + 2 * s), tre, tim);
            node_any(cBre, cBim, tre, tim, x2, gptr(gate_g, 992 + s), rootre, rootim);
        }
    }

    // round-5 subtree roots -> LDS
    s_t[s][lane] = make_float4(rootre.x, rootre.y, rootim.x, rootim.y);
    __syncthreads();

    // round 6: nodes 1008..1015, one per wave s<8
    if (s < 8) {
        float4 a = s_t[2 * s][lane], b = s_t[2 * s + 1][lane];
        v2f rre, rim;
        node_any((v2f){a.x, a.y}, (v2f){a.z, a.w}, (v2f){b.x, b.y}, (v2f){b.z, b.w},
                 x2, gptr(gate_g, 1008 + s), rre, rim);
        s_t[16 + s][lane] = make_float4(rre.x, rre.y, rim.x, rim.y);
    }
    __syncthreads();

    // round 7: nodes 1016..1019, waves s<4
    if (s < 4) {
        float4 a = s_t[16 + 2 * s][lane], b = s_t[17 + 2 * s][lane];
        v2f rre, rim;
        node_any((v2f){a.x, a.y}, (v2f){a.z, a.w}, (v2f){b.x, b.y}, (v2f){b.z, b.w},
                 x2, gptr(gate_g, 1016 + s), rre, rim);
        s_t[24 + s][lane] = make_float4(rre.x, rre.y, rim.x, rim.y);
    }
    __syncthreads();

    // round 8: nodes 1020, 1021, waves s<2
    if (s < 2) {
        float4 a = s_t[24 + 2 * s][lane], b = s_t[25 + 2 * s][lane];
        v2f rre, rim;
        node_any((v2f){a.x, a.y}, (v2f){a.z, a.w}, (v2f){b.x, b.y}, (v2f){b.z, b.w},
                 x2, gptr(gate_g, 1020 + s), rre, rim);
        s_t[28 + s][lane] = make_float4(rre.x, rre.y, rim.x, rim.y);
    }
    __syncthreads();

    // round 9: node 1022 -> output (wave 0)
    if (s == 0) {
        float4 a = s_t[28][lane], b = s_t[29][lane];
        v2f rre, rim;
        node_any((v2f){a.x, a.y}, (v2f){a.z, a.w}, (v2f){b.x, b.y}, (v2f){b.z, b.w},
                 x2, gptr(gate_g, 1022), rre, rim);
        if (out_real_only) {
            out[e0]      = rre.x;
            out[e0 + 64] = rre.y;
        } else {
            reinterpret_cast<float2*>(out)[e0]      = make_float2(rre.x, rim.x);
            reinterpret_cast<float2*>(out)[e0 + 64] = make_float2(rre.y, rim.y);
        }
    }
}

extern "C" void kernel_launch(void* const* d_in, const int* in_sizes, int n_in,
                              void* d_out, int out_size, void* d_ws, size_t ws_size,
                              hipStream_t stream) {
    const float* x    = (const float*)d_in[0];
    const float* leaf = (const float*)d_in[1];
    const float* gate = (const float*)d_in[2];
    float* out = (float*)d_out;
    const int batch = in_sizes[0];

    const int out_real_only = (out_size == batch) ? 1 : 0;

    dim3 block(64, 16);
    dim3 grid(batch / 128);
    hipLaunchKernelGGL(EMLTree1DLinear_kernel, grid, block, 0, stream,
                       x, leaf, gate, out, batch, out_real_only);
}